// Round 4
// baseline (192.147 us; speedup 1.0000x reference)
//
#include <hip/hip_runtime.h>
#include <hip/hip_cooperative_groups.h>
#include <math.h>

namespace cg = cooperative_groups;

#define N_AGENTS 1024
#define HID      128
#define SGRID    32
#define NCELL    1024
#define KDIM     2048      // n-extent of Y = 16*128
#define OUT_DIM  128

typedef __attribute__((ext_vector_type(8))) short bf16x8;  // 8 bf16 in 4 VGPRs
typedef __attribute__((ext_vector_type(4))) float f32x4;

__device__ inline unsigned short f2bf(float x) {
  unsigned int u = __float_as_uint(x);            // RNE fp32 -> bf16
  return (unsigned short)((u + 0x7FFFu + ((u >> 16) & 1u)) >> 16);
}
__device__ inline float bf2f(unsigned short h) {
  return __uint_as_float(((unsigned int)h) << 16);
}

// ---------------------------------------------------------------------------
// Algebra (R1/R2, kept):
//   out[i,o] = relu(b[o] + sum_e Y[j_e, g_e*128+o]),  e = winner cells of ego i
//   Y[j, g*128+o] = sum_h hidden[j][h] * W[o][h*16+g]  (ego-independent GEMM)
// R3: single cooperative launch (3 phases, 2 grid syncs) + Y stored as bf16.
// Winner semantics: numpy scatter last-writer-wins == max j (verified R0).
// ---------------------------------------------------------------------------
__global__ __launch_bounds__(256) void fused_kernel(
    const float* __restrict__ hidden,
    const float* __restrict__ obs2,
    const float* __restrict__ W,
    const float* __restrict__ bias,
    float* __restrict__ out,
    unsigned short* __restrict__ WB,   // [2048][128] bf16: WB[g*128+o][h]
    unsigned short* __restrict__ Ha,   // [1024][128] bf16 hidden
    unsigned short* __restrict__ Yb) { // [1024][2048] bf16 Y
  cg::grid_group grid = cg::this_grid();
  const int bid = blockIdx.x;          // 512 blocks
  const int t   = threadIdx.x;         // 256 threads

  // ---- Phase 1: operand prep (bf16 convert + W reorder) -------------------
  if (bid < 128) {                     // one block per W row o
    const int o  = bid;
    const int g  = t >> 4;             // 0..15
    const int h0 = (t & 15) * 8;       // 0,8,..,120
    const float* __restrict__ wrow = W + (size_t)o * KDIM;
    unsigned short tmp[8];
#pragma unroll
    for (int j = 0; j < 8; ++j) tmp[j] = f2bf(wrow[(h0 + j) * 16 + g]);
    unsigned short* dst = WB + (size_t)(g * 128 + o) * HID + h0;
    *(ushort4*)(dst)     = make_ushort4(tmp[0], tmp[1], tmp[2], tmp[3]);
    *(ushort4*)(dst + 4) = make_ushort4(tmp[4], tmp[5], tmp[6], tmp[7]);
  } else if (bid < 256) {              // hidden -> bf16, one float4 per thread
    const int idx = ((bid - 128) * 256 + t) * 4;
    float4 v = *(const float4*)(hidden + idx);
    *(ushort4*)(Ha + idx) =
        make_ushort4(f2bf(v.x), f2bf(v.y), f2bf(v.z), f2bf(v.w));
  }
  grid.sync();

  // ---- Phase 2: Y = Ha @ WB^T via v_mfma_f32_16x16x32_bf16 ----------------
  // Block = 4 waves = 64(m) x 64(n); K=128 -> 4 MFMA steps; fragments are
  // direct 16B global loads. C/D: col=lane&15, row=quad*4+reg.
  {
    const int lane = t & 63;
    const int wave = t >> 6;
    const int quad = lane >> 4;
    const int l16  = lane & 15;
    const int m0 = (bid >> 5) * 64 + wave * 16;
    const int n0 = (bid & 31) * 64;

    const unsigned short* pa  = Ha + (size_t)(m0 + l16) * HID + quad * 8;
    const unsigned short* pb0 = WB + (size_t)(n0 +  0 + l16) * HID + quad * 8;
    const unsigned short* pb1 = WB + (size_t)(n0 + 16 + l16) * HID + quad * 8;
    const unsigned short* pb2 = WB + (size_t)(n0 + 32 + l16) * HID + quad * 8;
    const unsigned short* pb3 = WB + (size_t)(n0 + 48 + l16) * HID + quad * 8;

    f32x4 acc0 = {0.f, 0.f, 0.f, 0.f};
    f32x4 acc1 = acc0, acc2 = acc0, acc3 = acc0;
#pragma unroll
    for (int s = 0; s < 4; ++s) {
      bf16x8 a  = *(const bf16x8*)(pa  + s * 32);
      bf16x8 b0 = *(const bf16x8*)(pb0 + s * 32);
      bf16x8 b1 = *(const bf16x8*)(pb1 + s * 32);
      bf16x8 b2 = *(const bf16x8*)(pb2 + s * 32);
      bf16x8 b3 = *(const bf16x8*)(pb3 + s * 32);
      acc0 = __builtin_amdgcn_mfma_f32_16x16x32_bf16(a, b0, acc0, 0, 0, 0);
      acc1 = __builtin_amdgcn_mfma_f32_16x16x32_bf16(a, b1, acc1, 0, 0, 0);
      acc2 = __builtin_amdgcn_mfma_f32_16x16x32_bf16(a, b2, acc2, 0, 0, 0);
      acc3 = __builtin_amdgcn_mfma_f32_16x16x32_bf16(a, b3, acc3, 0, 0, 0);
    }
    unsigned short* yrow = Yb + (size_t)(m0 + quad * 4) * KDIM + n0 + l16;
#pragma unroll
    for (int r = 0; r < 4; ++r) {
      yrow[r * KDIM +  0] = f2bf(acc0[r]);
      yrow[r * KDIM + 16] = f2bf(acc1[r]);
      yrow[r * KDIM + 32] = f2bf(acc2[r]);
      yrow[r * KDIM + 48] = f2bf(acc3[r]);
    }
  }
  grid.sync();

  // ---- Phase 3: per-ego winner scan + gather-sum + bias + relu ------------
  __shared__ int win[NCELL];
  __shared__ int s_cnt;
  __shared__ int s_off[NCELL];        // Yb offsets j*2048 + g*128
  __shared__ float part[128];

  const float2* o2 = (const float2*)obs2;
#pragma unroll 1
  for (int rep = 0; rep < 2; ++rep) {
    const int i = bid + rep * 512;

    for (int c = t; c < NCELL; c += 256) win[c] = -1;
    if (t == 0) s_cnt = 0;
    const float2 oi = o2[i];
    __syncthreads();

#pragma unroll 1
    for (int j = t; j < N_AGENTS; j += 256) {
      if (j == i) continue;
      float2 oj = o2[j];
      float fx = (oj.x - oi.x) * 4.0f + 16.0f;   // /0.25 exact
      float fy = (oj.y - oi.y) * 4.0f + 16.0f;
      // NaN coords fail the range test, matching the ok-masks
      if (fx >= 0.0f && fx < 32.0f && fy >= 0.0f && fy < 32.0f) {
        int cx = (int)fx, cy = (int)fy;          // trunc == floor (non-neg)
        atomicMax(&win[cx * SGRID + cy], j);
      }
    }
    __syncthreads();

    for (int c = t; c < NCELL; c += 256) {
      int j = win[c];
      if (j >= 0) {
        int cx = c >> 5, cy = c & 31;
        int g = ((cx >> 3) << 2) | (cy >> 3);
        int pos = atomicAdd(&s_cnt, 1);
        s_off[pos] = j * KDIM + g * 128;
      }
    }
    __syncthreads();

    const int cnt = s_cnt;
    const int o   = t & 127;
    const int par = t >> 7;           // 2 partitions over winner entries
    float a0 = 0.f, a1 = 0.f;
    int e = par;
    for (; e + 2 < cnt; e += 4) {     // 2 loads in flight per partition
      a0 += bf2f(Yb[s_off[e] + o]);
      a1 += bf2f(Yb[s_off[e + 2] + o]);
    }
    for (; e < cnt; e += 2) a0 += bf2f(Yb[s_off[e] + o]);
    float a = a0 + a1;
    if (par) part[o] = a;
    __syncthreads();
    if (t < 128) {
      float acc = bias[t] + a + part[t];
      out[i * OUT_DIM + t] = fmaxf(acc, 0.0f);
    }
    __syncthreads();                  // before win[] reuse next rep
  }
}

// ---------------------------------------------------------------------------
extern "C" void kernel_launch(void* const* d_in, const int* in_sizes, int n_in,
                              void* d_out, int out_size, void* d_ws, size_t ws_size,
                              hipStream_t stream) {
  const float* hidden = (const float*)d_in[0];
  // d_in[1] = obs1 (unused by the reference)
  const float* obs2 = (const float*)d_in[2];
  const float* W    = (const float*)d_in[3];
  const float* bias = (const float*)d_in[4];
  float* out = (float*)d_out;

  unsigned short* Yb = (unsigned short*)d_ws;                            // 4 MB
  unsigned short* WB = (unsigned short*)((char*)d_ws + 4u * 1024 * 1024); // 0.5 MB
  unsigned short* Ha = (unsigned short*)((char*)d_ws + 4608u * 1024);     // 0.25 MB

  void* args[] = {(void*)&hidden, (void*)&obs2, (void*)&W, (void*)&bias,
                  (void*)&out, (void*)&WB, (void*)&Ha, (void*)&Yb};
  hipLaunchCooperativeKernel((const void*)fused_kernel, dim3(512), dim3(256),
                             args, 0, stream);
}

// Round 5
// 73.489 us; speedup vs baseline: 2.6146x; 2.6146x over previous
//
#include <hip/hip_runtime.h>
#include <math.h>

#define N_AGENTS 1024
#define HID      128
#define SGRID    32
#define NCELL    1024
#define KDIM     2048      // n-extent of Y = 16*128
#define OUT_DIM  128

typedef __attribute__((ext_vector_type(8))) short bf16x8;  // 8 bf16 in 4 VGPRs
typedef __attribute__((ext_vector_type(4))) float f32x4;

__device__ inline unsigned short f2bf(float x) {
  unsigned int u = __float_as_uint(x);            // RNE fp32 -> bf16
  return (unsigned short)((u + 0x7FFFu + ((u >> 16) & 1u)) >> 16);
}
__device__ inline float bf2f(unsigned short h) {
  return __uint_as_float(((unsigned int)h) << 16);
}

// ---------------------------------------------------------------------------
// Algebra (R1/R2): out[i,o] = relu(b[o] + sum_e Y[j_e, g_e*128+o]) where
// Y[j, g*128+o] = sum_h hidden[j][h] * W[o][h*16+g]  (ego-independent GEMM,
// bf16 MFMA).  R4: back to 3 separate dispatches (R3's cooperative grid.sync
// cost ~50us/sync -- fixed harness overhead is ~72us and kernels are ~4us, so
// fusion has nothing to win); keep bf16 Y storage from R3.
// ---------------------------------------------------------------------------

// Kernel 1 (prep): WB[g*128+o][h] = bf16(W[o][h*16+g]) (B operand, n-major,
// k-contiguous -> direct 16B MFMA B-frag loads), and Ha = bf16(hidden).
__global__ __launch_bounds__(256) void prep_kernel(
    const float* __restrict__ W, const float* __restrict__ hidden,
    unsigned short* __restrict__ WB, unsigned short* __restrict__ Ha) {
  const int bid = blockIdx.x;
  const int t = threadIdx.x;
  if (bid < 128) {
    const int o = bid;
    const int g = t >> 4;            // 0..15
    const int h0 = (t & 15) * 8;     // 0,8,..,120
    const float* __restrict__ wrow = W + (size_t)o * KDIM;
    unsigned short tmp[8];
#pragma unroll
    for (int j = 0; j < 8; ++j) tmp[j] = f2bf(wrow[(h0 + j) * 16 + g]);
    unsigned short* dst = WB + (size_t)(g * 128 + o) * HID + h0;
    *(ushort4*)(dst)     = make_ushort4(tmp[0], tmp[1], tmp[2], tmp[3]);
    *(ushort4*)(dst + 4) = make_ushort4(tmp[4], tmp[5], tmp[6], tmp[7]);
  } else {
    const int i0 = (bid - 128) * 8192;
#pragma unroll
    for (int r = 0; r < 8; ++r) {
      int idx = i0 + r * 1024 + t * 4;
      float4 v = *(const float4*)(hidden + idx);
      *(ushort4*)(Ha + idx) = make_ushort4(f2bf(v.x), f2bf(v.y), f2bf(v.z), f2bf(v.w));
    }
  }
}

// Kernel 2: Y[j][n] = Ha[j][:] @ WB[n][:] via v_mfma_f32_16x16x32_bf16.
// Block = 4 waves = 64(m) x 64(n); K=128 -> 4 MFMA steps; fragments direct
// 16B global loads. C/D: col=lane&15, row=quad*4+reg (verified layout).
__global__ __launch_bounds__(256) void ygemm_kernel(
    const unsigned short* __restrict__ Ha,
    const unsigned short* __restrict__ WB,
    unsigned short* __restrict__ Yb) {
  const int lane = threadIdx.x & 63;
  const int wave = threadIdx.x >> 6;   // 0..3
  const int quad = lane >> 4;          // 0..3
  const int l16  = lane & 15;
  const int m0 = blockIdx.y * 64 + wave * 16;
  const int n0 = blockIdx.x * 64;

  const unsigned short* pa  = Ha + (size_t)(m0 + l16) * HID + quad * 8;
  const unsigned short* pb0 = WB + (size_t)(n0 +  0 + l16) * HID + quad * 8;
  const unsigned short* pb1 = WB + (size_t)(n0 + 16 + l16) * HID + quad * 8;
  const unsigned short* pb2 = WB + (size_t)(n0 + 32 + l16) * HID + quad * 8;
  const unsigned short* pb3 = WB + (size_t)(n0 + 48 + l16) * HID + quad * 8;

  f32x4 acc0 = {0.f, 0.f, 0.f, 0.f};
  f32x4 acc1 = acc0, acc2 = acc0, acc3 = acc0;
#pragma unroll
  for (int s = 0; s < 4; ++s) {
    bf16x8 a  = *(const bf16x8*)(pa  + s * 32);
    bf16x8 b0 = *(const bf16x8*)(pb0 + s * 32);
    bf16x8 b1 = *(const bf16x8*)(pb1 + s * 32);
    bf16x8 b2 = *(const bf16x8*)(pb2 + s * 32);
    bf16x8 b3 = *(const bf16x8*)(pb3 + s * 32);
    acc0 = __builtin_amdgcn_mfma_f32_16x16x32_bf16(a, b0, acc0, 0, 0, 0);
    acc1 = __builtin_amdgcn_mfma_f32_16x16x32_bf16(a, b1, acc1, 0, 0, 0);
    acc2 = __builtin_amdgcn_mfma_f32_16x16x32_bf16(a, b2, acc2, 0, 0, 0);
    acc3 = __builtin_amdgcn_mfma_f32_16x16x32_bf16(a, b3, acc3, 0, 0, 0);
  }
  unsigned short* yrow = Yb + (size_t)(m0 + quad * 4) * KDIM + n0 + l16;
#pragma unroll
  for (int r = 0; r < 4; ++r) {
    yrow[r * KDIM +  0] = f2bf(acc0[r]);
    yrow[r * KDIM + 16] = f2bf(acc1[r]);
    yrow[r * KDIM + 32] = f2bf(acc2[r]);
    yrow[r * KDIM + 48] = f2bf(acc3[r]);
  }
}

// Kernel 3: per-ego winner scan + 4-way-split gather of bf16 Y rows + bias +
// relu. Winner semantics: numpy scatter last-writer-wins == max j (R0).
__global__ __launch_bounds__(512) void social_kernel(
    const float* __restrict__ obs2,
    const unsigned short* __restrict__ Yb,
    const float* __restrict__ bias,
    float* __restrict__ out) {
  const int i = blockIdx.x;
  const int t = threadIdx.x;
  __shared__ int win[NCELL];
  __shared__ int s_cnt;
  __shared__ int s_off[NCELL];      // Yb offsets j*2048 + g*128
  __shared__ float part[3][128];

  for (int c = t; c < NCELL; c += 512) win[c] = -1;
  if (t == 0) s_cnt = 0;
  const float2* o2 = (const float2*)obs2;
  const float2 oi = o2[i];
  __syncthreads();

  for (int j = t; j < N_AGENTS; j += 512) {
    if (j == i) continue;
    float2 oj = o2[j];
    float fx = (oj.x - oi.x) * 4.0f + 16.0f;   // /0.25 exact
    float fy = (oj.y - oi.y) * 4.0f + 16.0f;
    // NaN coords fail the range test, matching the ok-masks
    if (fx >= 0.0f && fx < 32.0f && fy >= 0.0f && fy < 32.0f) {
      int cx = (int)fx, cy = (int)fy;          // trunc == floor (non-neg)
      atomicMax(&win[cx * SGRID + cy], j);
    }
  }
  __syncthreads();

  for (int c = t; c < NCELL; c += 512) {
    int j = win[c];
    if (j >= 0) {
      int cx = c >> 5, cy = c & 31;
      int g = ((cx >> 3) << 2) | (cy >> 3);
      int pos = atomicAdd(&s_cnt, 1);
      s_off[pos] = j * KDIM + g * 128;
    }
  }
  __syncthreads();

  const int cnt = s_cnt;
  const int o = t & 127;
  const int par = t >> 7;           // 4 partitions over winner entries
  float a0 = 0.f, a1 = 0.f;
  int e = par;
  for (; e + 4 < cnt; e += 8) {     // 2 loads in flight per partition
    a0 += bf2f(Yb[s_off[e] + o]);
    a1 += bf2f(Yb[s_off[e + 4] + o]);
  }
  for (; e < cnt; e += 4) a0 += bf2f(Yb[s_off[e] + o]);
  float a = a0 + a1;
  if (par) part[par - 1][o] = a;
  __syncthreads();
  if (t < 128) {
    float acc = bias[t] + a + part[0][t] + part[1][t] + part[2][t];
    out[i * OUT_DIM + t] = fmaxf(acc, 0.0f);
  }
}

// ---------------------------------------------------------------------------
extern "C" void kernel_launch(void* const* d_in, const int* in_sizes, int n_in,
                              void* d_out, int out_size, void* d_ws, size_t ws_size,
                              hipStream_t stream) {
  const float* hidden = (const float*)d_in[0];
  // d_in[1] = obs1 (unused by the reference)
  const float* obs2 = (const float*)d_in[2];
  const float* W    = (const float*)d_in[3];
  const float* bias = (const float*)d_in[4];
  float* out = (float*)d_out;

  unsigned short* Yb = (unsigned short*)d_ws;                             // 4 MB
  unsigned short* WB = (unsigned short*)((char*)d_ws + 4u * 1024 * 1024); // 0.5 MB
  unsigned short* Ha = (unsigned short*)((char*)d_ws + 4608u * 1024);     // 0.25 MB

  hipLaunchKernelGGL(prep_kernel, dim3(144), dim3(256), 0, stream,
                     W, hidden, WB, Ha);
  hipLaunchKernelGGL(ygemm_kernel, dim3(KDIM / 64, N_AGENTS / 64), dim3(256),
                     0, stream, Ha, WB, Yb);
  hipLaunchKernelGGL(social_kernel, dim3(N_AGENTS), dim3(512), 0, stream,
                     obs2, Yb, bias, out);
}